// Round 19
// baseline (192.886 us; speedup 1.0000x reference)
//
#include <hip/hip_runtime.h>
#include <hip/hip_fp8.h>
#include <cstdint>

#define BB 32768
#define II 1024
#define HH 1024
#define SPLIT 16
#define KCH (BB/SPLIT)      // 2048
#define NT1 (II/64)         // 16 K-tiles (gemm1)
#define NT2 (KCH/64)        // 32 K-tiles per split (gemm2)

typedef _Float16 f16;
typedef _Float16 f16x4 __attribute__((ext_vector_type(4)));
typedef _Float16 f16x8 __attribute__((ext_vector_type(8)));
typedef float f32x4 __attribute__((ext_vector_type(4)));

typedef const __attribute__((address_space(1))) void gvoid_t;
typedef __attribute__((address_space(3))) void lvoid_t;

__device__ __forceinline__ void gload16(const void* g, void* l){
    __builtin_amdgcn_global_load_lds((gvoid_t*)g, (lvoid_t*)l, 16, 0, 0);
}

__device__ __forceinline__ float tanh_fast(float s){
    float a = fabsf(s);
    float e = __expf(-2.0f * a);
    float t = __fdividef(1.0f - e, 1.0f + e);
    return s < 0.0f ? -t : t;
}

__device__ __forceinline__ unsigned char f2fp8(float v){
    __hip_fp8_e4m3 q(v);
    return (unsigned char)q.__x;
}

__device__ __forceinline__ float fp82f(unsigned char b){
    __hip_fp8_e4m3 q;
    q.__x = b;
    return (float)q;
}

// Fused prep: blocks [0,512): x [B][I] -> xf f16 + xt8 fp8 [I][B]
//             blocks [512,528): W [I][H] -> wt f16 [H][I]
__global__ __launch_bounds__(256) void k_prep2(const float* __restrict__ x,
                                               f16* __restrict__ xf,
                                               unsigned char* __restrict__ xt8,
                                               const float* __restrict__ W,
                                               f16* __restrict__ wt){
    __shared__ float lt[64*67];
    const int t = threadIdx.x;
    const int bx = (int)blockIdx.x;
    const bool isX = (bx < 512);
    const float* in = isX ? x : W;
    const int C = isX ? II : HH, R = isX ? BB : II;
    const int r0 = (isX ? bx : bx-512)*64;
    const int c0 = blockIdx.y*64;
    #pragma unroll
    for (int p=0; p<4; ++p){
        int r = p*16 + (t>>4);
        int c = (t&15)*4;
        f32x4 v = __builtin_nontemporal_load((const f32x4*)&in[(size_t)(r0+r)*C + c0 + c]);
        if (isX){
            f16x4 hv = {(f16)v[0],(f16)v[1],(f16)v[2],(f16)v[3]};
            *(f16x4*)&xf[(size_t)(r0+r)*C + c0 + c] = hv;
        }
        lt[r*67 + c+0] = v[0];
        lt[r*67 + c+1] = v[1];
        lt[r*67 + c+2] = v[2];
        lt[r*67 + c+3] = v[3];
    }
    __syncthreads();
    const int c = t>>2, rb = (t&3)*16;
    if (isX){
        union { unsigned char cb[16]; f32x4 v4; } u;
        #pragma unroll
        for (int e=0; e<16; ++e) u.cb[e] = f2fp8(lt[(rb+e)*67 + c]);
        *(f32x4*)&xt8[(size_t)(c0+c)*R + r0 + rb] = u.v4;
    } else {
        f16x8 a, b;
        #pragma unroll
        for (int e=0; e<8; ++e) a[e] = (f16)lt[(rb+e)*67 + c];
        #pragma unroll
        for (int e=0; e<8; ++e) b[e] = (f16)lt[(rb+8+e)*67 + c];
        f16* o = &wt[(size_t)(c0+c)*R + r0 + rb];
        *(f16x8*)o = a;
        *(f16x8*)(o+8) = b;
    }
}

// ================= GEMM1 (f16, 8-phase, peeled last iteration) =================
__device__ __forceinline__ void stage_half(const f16* __restrict__ panel, int ld,
                                           int row0, int kcol0, char* lds_half,
                                           int wid, int lane){
    #pragma unroll
    for (int r=0;r<2;++r){
        int o = r*8192 + wid*1024 + lane*16;
        int rr = o>>7;
        int c0 = (o&127) ^ ((rr&7)<<4);
        gload16(panel + (size_t)(row0 + rr)*ld + kcol0 + (c0>>1), lds_half + r*8192 + wid*1024);
    }
}

#define RD_A(BUFA, mh) { \
    _Pragma("unroll") for (int m_=0;m_<4;++m_){ \
        af[m_][0] = *(const f16x8*)((BUFA) + rowA + (mh)*8192 + m_*2048 + ksw0); \
        af[m_][1] = *(const f16x8*)((BUFA) + rowA + (mh)*8192 + m_*2048 + ksw1); }}

#define RD_B(BUFB, nh) { \
    _Pragma("unroll") for (int n_=0;n_<2;++n_){ \
        bf[(nh)*2+n_][0] = *(const f16x8*)((BUFB) + rowB + (nh)*4096 + n_*2048 + ksw0); \
        bf[(nh)*2+n_][1] = *(const f16x8*)((BUFB) + rowB + (nh)*4096 + n_*2048 + ksw1); }}

#define MFMA_Q(mh,nh) { \
    __builtin_amdgcn_s_setprio(1); \
    _Pragma("unroll") for (int m_=0;m_<4;++m_){ \
      _Pragma("unroll") for (int n_=0;n_<2;++n_){ \
        _Pragma("unroll") for (int ks_=0;ks_<2;++ks_){ \
          acc[(mh)*4+m_][(nh)*2+n_] = __builtin_amdgcn_mfma_f32_16x16x32_f16( \
              af[m_][ks_], bf[(nh)*2+n_][ks_], acc[(mh)*4+m_][(nh)*2+n_], 0,0,0); }}} \
    __builtin_amdgcn_s_setprio(0); }

#define PH_SYNC1 { __builtin_amdgcn_s_barrier(); \
    asm volatile("s_waitcnt lgkmcnt(0)" ::: "memory"); \
    __builtin_amdgcn_sched_barrier(0); }
#define PH_SYNC2 { __builtin_amdgcn_s_barrier(); }
#define LGKM8 { asm volatile("s_waitcnt lgkmcnt(8)" ::: "memory"); }
#define LGKM0SB { asm volatile("s_waitcnt lgkmcnt(0)" ::: "memory"); \
    __builtin_amdgcn_sched_barrier(0); }

// per-quadrant fused epilogue: tanh + ht8 micro-tile u32 + hidden f32 scatter
#define EPI_Q(mh,nh) { \
    _Pragma("unroll") for (int m_=0;m_<4;++m_){ \
      const int b_ = b_base + ((mh)*4+m_)*16; \
      _Pragma("unroll") for (int n_=0;n_<2;++n_){ \
        const int h_ = h_base + ((nh)*2+n_)*16; \
        float t0 = tanh_fast(acc[(mh)*4+m_][(nh)*2+n_][0]); \
        float t1 = tanh_fast(acc[(mh)*4+m_][(nh)*2+n_][1]); \
        float t2 = tanh_fast(acc[(mh)*4+m_][(nh)*2+n_][2]); \
        float t3 = tanh_fast(acc[(mh)*4+m_][(nh)*2+n_][3]); \
        union { unsigned char cb[4]; unsigned int u; } p_; \
        p_.cb[0]=f2fp8(t0); p_.cb[1]=f2fp8(t1); p_.cb[2]=f2fp8(t2); p_.cb[3]=f2fp8(t3); \
        *(unsigned int*)&ht8[(((size_t)(h_>>4)*(BB>>4) + (b_>>4))<<8) + ((h_&15)<<4) + (b_&15)] = p_.u; \
        hidden[(size_t)(b_+0)*HH + h_] = t0; \
        hidden[(size_t)(b_+1)*HH + h_] = t1; \
        hidden[(size_t)(b_+2)*HH + h_] = t2; \
        hidden[(size_t)(b_+3)*HH + h_] = t3; \
    }}}

// GEMM1: hidden[b][h]=tanh(xf·wt); ht8 = fp8(tanh) micro-tiled [h>>4][b>>4][h&15][b&15].
__global__ __launch_bounds__(512,2) void k_gemm1(const f16* __restrict__ xf,
                                                 const f16* __restrict__ wt,
                                                 float* __restrict__ hidden,
                                                 unsigned char* __restrict__ ht8){
    __shared__ char sm[131072];
    const int bid = (int)blockIdx.x;
    const int swz = (bid & 7)*64 + (bid >> 3);
    const int btile = swz >> 2, htile = swz & 3;
    const int arow0 = btile*256, brow0 = htile*256;

    const int t = threadIdx.x, lane = t & 63, wid = t >> 6;
    const int wr = wid >> 2, wc = wid & 3;
    const int fr = lane & 15, kg = lane >> 4;
    char* const A0 = sm;
    char* const B0 = sm + 32768;
    char* const A1 = sm + 65536;
    char* const B1 = sm + 98304;
    const int rowA = wr*16384 + fr*128;
    const int rowB = (wc>>1)*16384 + (wc&1)*8192 + fr*128;
    const int ksw0 = ((kg    ) ^ (fr & 7)) << 4;
    const int ksw1 = ((kg + 4) ^ (fr & 7)) << 4;
    const int b_base = btile*256 + wr*128 + kg*4;
    const int h_base = htile*256 + wc*64 + fr;

    f32x4 acc[8][4] = {};
    f16x8 af[4][2], bf[4][2];

    // prologue: K0 -> buf0 (4 half-tiles), K1 -> B1 half0, A1 half0
    stage_half(xf, II, arow0 +   0,  0, A0,         wid, lane);
    stage_half(xf, II, arow0 + 128,  0, A0 + 16384, wid, lane);
    stage_half(wt, II, brow0 +   0,  0, B0,         wid, lane);
    stage_half(wt, II, brow0 + 128,  0, B0 + 16384, wid, lane);
    stage_half(wt, II, brow0 +   0, 64, B1,         wid, lane);
    stage_half(xf, II, arow0 +   0, 64, A1,         wid, lane);
    asm volatile("s_waitcnt vmcnt(4)" ::: "memory");
    __builtin_amdgcn_s_barrier();

    const int ni = NT1 >> 1;     // 8
    for (int it = 0; it < ni-1; ++it){       // main: K-tiles 0..13, stages 0..15 exactly once
        const int k1 = (2*it + 1) * 64;
        const int k2 = (2*it + 2) * 64;
        const int k3 = (2*it + 3) * 64;
        RD_A(A0, 0); RD_B(B0, 0);
        stage_half(xf, II, arow0 + 128, k1, A1 + 16384, wid, lane);
        LGKM8; PH_SYNC1; MFMA_Q(0,0); PH_SYNC2;
        RD_B(B0, 1);
        stage_half(wt, II, brow0 + 128, k1, B1 + 16384, wid, lane);
        PH_SYNC1; MFMA_Q(0,1); PH_SYNC2;
        RD_A(A0, 1);
        stage_half(wt, II, brow0 +   0, k2, B0, wid, lane);
        PH_SYNC1; MFMA_Q(1,0); PH_SYNC2;
        stage_half(xf, II, arow0 +   0, k2, A0, wid, lane);
        PH_SYNC1; MFMA_Q(1,1);
        asm volatile("s_waitcnt vmcnt(4)" ::: "memory");
        __builtin_amdgcn_s_barrier();
        RD_A(A1, 0); RD_B(B1, 0);
        stage_half(xf, II, arow0 + 128, k2, A0 + 16384, wid, lane);
        LGKM8; PH_SYNC1; MFMA_Q(0,0); PH_SYNC2;
        RD_B(B1, 1);
        stage_half(wt, II, brow0 + 128, k2, B0 + 16384, wid, lane);
        PH_SYNC1; MFMA_Q(0,1); PH_SYNC2;
        RD_A(A1, 1);
        stage_half(wt, II, brow0 +   0, k3, B1, wid, lane);
        PH_SYNC1; MFMA_Q(1,0); PH_SYNC2;
        stage_half(xf, II, arow0 +   0, k3, A1, wid, lane);
        PH_SYNC1; MFMA_Q(1,1);
        asm volatile("s_waitcnt vmcnt(4)" ::: "memory");
        __builtin_amdgcn_s_barrier();
    }

    // peeled tail: K-tiles 14 (buf0) and 15 (buf1); completes tile-15 halves,
    // then barrier-free finish with fused per-quadrant epilogue.
    {
        const int kL = (NT1-1)*64;           // 960
        RD_A(A0, 0); RD_B(B0, 0);
        stage_half(xf, II, arow0 + 128, kL, A1 + 16384, wid, lane);
        LGKM0SB; MFMA_Q(0,0);
        RD_B(B0, 1);
        stage_half(wt, II, brow0 + 128, kL, B1 + 16384, wid, lane);
        LGKM0SB; MFMA_Q(0,1);
        RD_A(A0, 1);
        LGKM0SB; MFMA_Q(1,0);
        MFMA_Q(1,1);
        asm volatile("s_waitcnt vmcnt(0)" ::: "memory");
        __builtin_amdgcn_s_barrier();
        RD_A(A1, 0); RD_B(B1, 0);
        LGKM0SB; MFMA_Q(0,0); EPI_Q(0,0);
        RD_B(B1, 1);
        LGKM0SB; MFMA_Q(0,1); EPI_Q(0,1);
        RD_A(A1, 1);
        LGKM0SB; MFMA_Q(1,0); EPI_Q(1,0);
        MFMA_Q(1,1); EPI_Q(1,1);
    }
}

// ================= GEMM2 (fp8 in, fp8 partials out) =================
template<bool MT>
__device__ __forceinline__ void stage_half8(const unsigned char* __restrict__ panel, int ld,
                                            int row0, int kcol0, char* lds_half,
                                            int wid, int lane){
    int o  = wid*1024 + lane*16;
    int rr = o>>6;
    int c  = (o&63) ^ ((rr&6)<<3);
    if constexpr (!MT){
        gload16(panel + (size_t)(row0+rr)*ld + kcol0 + c, lds_half + wid*1024);
    } else {
        int h = row0 + rr;
        int babs = kcol0 + c;
        gload16(panel + (((size_t)(h>>4)*(BB>>4) + (babs>>4))<<8) + ((h&15)<<4) + (babs&15),
                lds_half + wid*1024);
    }
}

#define RD_A8(BUFA, mh) { \
    _Pragma("unroll") for (int m_=0;m_<4;++m_){ \
        afl[m_][0] = *(const long*)((BUFA) + rowA8 + (mh)*4096 + m_*1024 + k80); \
        afl[m_][1] = *(const long*)((BUFA) + rowA8 + (mh)*4096 + m_*1024 + k81); }}

#define RD_B8(BUFB, nh) { \
    _Pragma("unroll") for (int n_=0;n_<2;++n_){ \
        bfl[(nh)*2+n_][0] = *(const long*)((BUFB) + rowB8 + (nh)*2048 + n_*1024 + k80); \
        bfl[(nh)*2+n_][1] = *(const long*)((BUFB) + rowB8 + (nh)*2048 + n_*1024 + k81); }}

#define MFMA_Q8(mh,nh) { \
    __builtin_amdgcn_s_setprio(1); \
    _Pragma("unroll") for (int m_=0;m_<4;++m_){ \
      _Pragma("unroll") for (int n_=0;n_<2;++n_){ \
        _Pragma("unroll") for (int ks_=0;ks_<2;++ks_){ \
          acc[(mh)*4+m_][(nh)*2+n_] = __builtin_amdgcn_mfma_f32_16x16x32_fp8_fp8( \
              afl[m_][ks_], bfl[(nh)*2+n_][ks_], acc[(mh)*4+m_][(nh)*2+n_], 0,0,0); }}} \
    __builtin_amdgcn_s_setprio(0); }

__global__ __launch_bounds__(512,2) void k_gemm2(const unsigned char* __restrict__ xt8,
                                                 const unsigned char* __restrict__ ht8,
                                                 unsigned char* __restrict__ part){
    __shared__ char sm[65536];           // A0 16K | B0 16K | A1 16K | B1 16K
    const int bid = (int)blockIdx.x;
    const int swz = (bid & 7)*32 + (bid >> 3);
    const int split = swz >> 4, tile = swz & 15;
    const int itile = tile & 3, htile = tile >> 2;
    const int arow0 = itile*256, brow0 = htile*256, kbase = split*KCH;

    const int t = threadIdx.x, lane = t & 63, wid = t >> 6;
    const int wr = wid >> 2, wc = wid & 3;
    const int fr = lane & 15, kg = lane >> 4;
    const int mask = NT2 - 1;
    char* const A0 = sm;
    char* const B0 = sm + 16384;
    char* const A1 = sm + 32768;
    char* const B1 = sm + 49152;
    const int rowA8 = wr*8192 + fr*64;
    const int rowB8 = (wc>>1)*8192 + (wc&1)*4096 + fr*64;
    const int s6  = fr & 6;
    const int k80 = ((kg    ) ^ s6) << 3;
    const int k81 = ((kg + 4) ^ s6) << 3;

    f32x4 acc[8][4] = {};
    long afl[4][2], bfl[4][2];

    stage_half8<false>(xt8, BB, arow0 +   0, kbase +  0, A0,        wid, lane);
    stage_half8<false>(xt8, BB, arow0 + 128, kbase +  0, A0 + 8192, wid, lane);
    stage_half8<true >(ht8, BB, brow0 +   0, kbase +  0, B0,        wid, lane);
    stage_half8<true >(ht8, BB, brow0 + 128, kbase +  0, B0 + 8192, wid, lane);
    stage_half8<true >(ht8, BB, brow0 +   0, kbase + 64, B1,        wid, lane);
    stage_half8<false>(xt8, BB, arow0 +   0, kbase + 64, A1,        wid, lane);
    asm volatile("s_waitcnt vmcnt(2)" ::: "memory");
    __builtin_amdgcn_s_barrier();

    const int ni = NT2 >> 1;
    for (int it = 0; it < ni; ++it){
        const int k1 = (2*it + 1) * 64;
        const int k2 = ((2*it + 2) & mask) * 64;
        const int k3 = ((2*it + 3) & mask) * 64;
        RD_A8(A0, 0); RD_B8(B0, 0);
        stage_half8<false>(xt8, BB, arow0 + 128, kbase + k1, A1 + 8192, wid, lane);
        PH_SYNC1; MFMA_Q8(0,0); PH_SYNC2;
        RD_B8(B0, 1);
        stage_half8<true>(ht8, BB, brow0 + 128, kbase + k1, B1 + 8192, wid, lane);
        PH_SYNC1; MFMA_Q8(0,1); PH_SYNC2;
        RD_A8(A0, 1);
        stage_half8<true>(ht8, BB, brow0 +   0, kbase + k2, B0, wid, lane);
        PH_SYNC1; MFMA_Q8(1,0); PH_SYNC2;
        stage_half8<false>(xt8, BB, arow0 +   0, kbase + k2, A0, wid, lane);
        PH_SYNC1; MFMA_Q8(1,1);
        asm volatile("s_waitcnt vmcnt(2)" ::: "memory");
        __builtin_amdgcn_s_barrier();
        RD_A8(A1, 0); RD_B8(B1, 0);
        stage_half8<false>(xt8, BB, arow0 + 128, kbase + k2, A0 + 8192, wid, lane);
        PH_SYNC1; MFMA_Q8(0,0); PH_SYNC2;
        RD_B8(B1, 1);
        stage_half8<true>(ht8, BB, brow0 + 128, kbase + k2, B0 + 8192, wid, lane);
        PH_SYNC1; MFMA_Q8(0,1); PH_SYNC2;
        RD_A8(A1, 1);
        stage_half8<true>(ht8, BB, brow0 +   0, kbase + k3, B1, wid, lane);
        PH_SYNC1; MFMA_Q8(1,0); PH_SYNC2;
        stage_half8<false>(xt8, BB, arow0 +   0, kbase + k3, A1, wid, lane);
        PH_SYNC1; MFMA_Q8(1,1);
        asm volatile("s_waitcnt vmcnt(2)" ::: "memory");
        __builtin_amdgcn_s_barrier();
    }
    asm volatile("s_waitcnt vmcnt(0)" ::: "memory");
    __builtin_amdgcn_s_barrier();

    const size_t pb = (size_t)split*II*HH;
    #pragma unroll
    for (int mf=0; mf<8; ++mf){
        const int i0 = itile*256 + wr*128 + mf*16 + kg*4;
        #pragma unroll
        for (int nf=0; nf<4; ++nf){
            const int h = htile*256 + wc*64 + nf*16 + fr;
            union { unsigned char cb[4]; unsigned int u; } p;
            p.cb[0] = f2fp8(acc[mf][nf][0]);
            p.cb[1] = f2fp8(acc[mf][nf][1]);
            p.cb[2] = f2fp8(acc[mf][nf][2]);
            p.cb[3] = f2fp8(acc[mf][nf][3]);
            *(unsigned int*)&part[pb + (((size_t)(i0>>4)*(HH>>4) + (h>>4))<<8) + ((h&15)<<4) + (i0&15)] = p.u;
        }
    }
}

// k_final: sum 16 fp8 partial planes, apply clip(W + SCALE*delta). 16 elems/thread.
__global__ __launch_bounds__(256) void k_final(const unsigned char* __restrict__ part,
                                               const float* __restrict__ W,
                                               float* __restrict__ outW){
    const int T = (int)blockIdx.x*256 + threadIdx.x;   // 0..65535
    const int mt = T >> 4;                             // micro-tile (i>>4)*64+(h>>4)
    const int hl = T & 15;
    const int i0 = (mt >> 6)*16;
    const int h  = (mt & 63)*16 + hl;
    const size_t po = ((size_t)mt << 8) + (hl << 4);
    float s[16] = {};
    #pragma unroll
    for (int sp=0; sp<SPLIT; ++sp){
        union { f32x4 v; unsigned char cb[16]; } u;
        u.v = __builtin_nontemporal_load((const f32x4*)&part[(size_t)sp*1048576 + po]);
        #pragma unroll
        for (int e=0;e<16;++e) s[e] += fp82f(u.cb[e]);
    }
    const float SCALE = 3.0517578125e-07f;  // 0.01 / 32768
    #pragma unroll
    for (int e=0;e<16;++e){
        const size_t o = (size_t)(i0+e)*HH + h;
        float r = fminf(1.f, fmaxf(-1.f, fmaf(SCALE, s[e], W[o])));
        __builtin_nontemporal_store(r, &outW[o]);
    }
}

extern "C" void kernel_launch(void* const* d_in, const int* in_sizes, int n_in,
                              void* d_out, int out_size, void* d_ws, size_t ws_size,
                              hipStream_t stream){
    (void)in_sizes; (void)n_in; (void)out_size; (void)ws_size;
    const float* x = (const float*)d_in[0];
    const float* W = (const float*)d_in[1];
    float* hidden = (float*)d_out;
    float* outW   = hidden + (size_t)BB*HH;
    char* ws = (char*)d_ws;
    // ws: xf f16 @0 (64MB) | xt8 fp8 @64M (32MB) | ht8 fp8 @96M (32MB) | wt f16 @128M (2MB)
    //     part fp8 [16][I][H] (micro) @0 (16MB, overlaps dead xf)
    f16*           xf   = (f16*)(ws);
    unsigned char* xt8  = (unsigned char*)(ws + 67108864ull);
    unsigned char* ht8  = (unsigned char*)(ws + 100663296ull);
    f16*           wt   = (f16*)(ws + 134217728ull);
    unsigned char* part = (unsigned char*)(ws);

    k_prep2<<<dim3(528, 16), 256, 0, stream>>>(x, xf, xt8, W, wt);
    k_gemm1<<<dim3((BB/256)*(HH/256)), 512, 0, stream>>>(xf, wt, hidden, ht8);
    k_gemm2<<<dim3(16*SPLIT), 512, 0, stream>>>(xt8, ht8, part);
    k_final<<<dim3((II*HH)/(256*16)), 256, 0, stream>>>(part, W, outW);
}

// Round 20
// 192.210 us; speedup vs baseline: 1.0035x; 1.0035x over previous
//
#include <hip/hip_runtime.h>
#include <hip/hip_fp8.h>
#include <cstdint>

#define BB 32768
#define II 1024
#define HH 1024
#define SPLIT 16
#define KCH (BB/SPLIT)      // 2048
#define NT1 (II/64)         // 16 K-tiles (gemm1)
#define NT2 (KCH/64)        // 32 K-tiles per split (gemm2)

typedef _Float16 f16;
typedef _Float16 f16x4 __attribute__((ext_vector_type(4)));
typedef _Float16 f16x8 __attribute__((ext_vector_type(8)));
typedef float f32x4 __attribute__((ext_vector_type(4)));

typedef const __attribute__((address_space(1))) void gvoid_t;
typedef __attribute__((address_space(3))) void lvoid_t;

__device__ __forceinline__ void gload16(const void* g, void* l){
    __builtin_amdgcn_global_load_lds((gvoid_t*)g, (lvoid_t*)l, 16, 0, 0);
}

__device__ __forceinline__ float tanh_fast(float s){
    float a = fabsf(s);
    float e = __expf(-2.0f * a);
    float t = __fdividef(1.0f - e, 1.0f + e);
    return s < 0.0f ? -t : t;
}

__device__ __forceinline__ unsigned char f2fp8(float v){
    __hip_fp8_e4m3 q(v);
    return (unsigned char)q.__x;
}

__device__ __forceinline__ float fp82f(unsigned char b){
    __hip_fp8_e4m3 q;
    q.__x = b;
    return (float)q;
}

// Fused prep: blocks [0,512): x [B][I] -> xf f16 + xt8 fp8 [I][B]
//             blocks [512,528): W [I][H] -> wt f16 [H][I]
__global__ __launch_bounds__(256) void k_prep2(const float* __restrict__ x,
                                               f16* __restrict__ xf,
                                               unsigned char* __restrict__ xt8,
                                               const float* __restrict__ W,
                                               f16* __restrict__ wt){
    __shared__ float lt[64*67];
    const int t = threadIdx.x;
    const int bx = (int)blockIdx.x;
    const bool isX = (bx < 512);
    const float* in = isX ? x : W;
    const int C = isX ? II : HH, R = isX ? BB : II;
    const int r0 = (isX ? bx : bx-512)*64;
    const int c0 = blockIdx.y*64;
    #pragma unroll
    for (int p=0; p<4; ++p){
        int r = p*16 + (t>>4);
        int c = (t&15)*4;
        f32x4 v = __builtin_nontemporal_load((const f32x4*)&in[(size_t)(r0+r)*C + c0 + c]);
        if (isX){
            f16x4 hv = {(f16)v[0],(f16)v[1],(f16)v[2],(f16)v[3]};
            *(f16x4*)&xf[(size_t)(r0+r)*C + c0 + c] = hv;
        }
        lt[r*67 + c+0] = v[0];
        lt[r*67 + c+1] = v[1];
        lt[r*67 + c+2] = v[2];
        lt[r*67 + c+3] = v[3];
    }
    __syncthreads();
    const int c = t>>2, rb = (t&3)*16;
    if (isX){
        union { unsigned char cb[16]; f32x4 v4; } u;
        #pragma unroll
        for (int e=0; e<16; ++e) u.cb[e] = f2fp8(lt[(rb+e)*67 + c]);
        *(f32x4*)&xt8[(size_t)(c0+c)*R + r0 + rb] = u.v4;
    } else {
        f16x8 a, b;
        #pragma unroll
        for (int e=0; e<8; ++e) a[e] = (f16)lt[(rb+e)*67 + c];
        #pragma unroll
        for (int e=0; e<8; ++e) b[e] = (f16)lt[(rb+8+e)*67 + c];
        f16* o = &wt[(size_t)(c0+c)*R + r0 + rb];
        *(f16x8*)o = a;
        *(f16x8*)(o+8) = b;
    }
}

// ================= GEMM1 (f16, 8-phase, peeled last iteration) =================
__device__ __forceinline__ void stage_half(const f16* __restrict__ panel, int ld,
                                           int row0, int kcol0, char* lds_half,
                                           int wid, int lane){
    #pragma unroll
    for (int r=0;r<2;++r){
        int o = r*8192 + wid*1024 + lane*16;
        int rr = o>>7;
        int c0 = (o&127) ^ ((rr&7)<<4);
        gload16(panel + (size_t)(row0 + rr)*ld + kcol0 + (c0>>1), lds_half + r*8192 + wid*1024);
    }
}

#define RD_A(BUFA, mh) { \
    _Pragma("unroll") for (int m_=0;m_<4;++m_){ \
        af[m_][0] = *(const f16x8*)((BUFA) + rowA + (mh)*8192 + m_*2048 + ksw0); \
        af[m_][1] = *(const f16x8*)((BUFA) + rowA + (mh)*8192 + m_*2048 + ksw1); }}

#define RD_B(BUFB, nh) { \
    _Pragma("unroll") for (int n_=0;n_<2;++n_){ \
        bf[(nh)*2+n_][0] = *(const f16x8*)((BUFB) + rowB + (nh)*4096 + n_*2048 + ksw0); \
        bf[(nh)*2+n_][1] = *(const f16x8*)((BUFB) + rowB + (nh)*4096 + n_*2048 + ksw1); }}

#define MFMA_Q(mh,nh) { \
    __builtin_amdgcn_s_setprio(1); \
    _Pragma("unroll") for (int m_=0;m_<4;++m_){ \
      _Pragma("unroll") for (int n_=0;n_<2;++n_){ \
        _Pragma("unroll") for (int ks_=0;ks_<2;++ks_){ \
          acc[(mh)*4+m_][(nh)*2+n_] = __builtin_amdgcn_mfma_f32_16x16x32_f16( \
              af[m_][ks_], bf[(nh)*2+n_][ks_], acc[(mh)*4+m_][(nh)*2+n_], 0,0,0); }}} \
    __builtin_amdgcn_s_setprio(0); }

#define PH_SYNC1 { __builtin_amdgcn_s_barrier(); \
    asm volatile("s_waitcnt lgkmcnt(0)" ::: "memory"); \
    __builtin_amdgcn_sched_barrier(0); }
#define PH_SYNC2 { __builtin_amdgcn_s_barrier(); }
#define LGKM8 { asm volatile("s_waitcnt lgkmcnt(8)" ::: "memory"); }
#define LGKM0SB { asm volatile("s_waitcnt lgkmcnt(0)" ::: "memory"); \
    __builtin_amdgcn_sched_barrier(0); }

// per-quadrant fused epilogue: tanh + ht8 micro-tile u32 + hidden f32 scatter
#define EPI_Q(mh,nh) { \
    _Pragma("unroll") for (int m_=0;m_<4;++m_){ \
      const int b_ = b_base + ((mh)*4+m_)*16; \
      _Pragma("unroll") for (int n_=0;n_<2;++n_){ \
        const int h_ = h_base + ((nh)*2+n_)*16; \
        float t0 = tanh_fast(acc[(mh)*4+m_][(nh)*2+n_][0]); \
        float t1 = tanh_fast(acc[(mh)*4+m_][(nh)*2+n_][1]); \
        float t2 = tanh_fast(acc[(mh)*4+m_][(nh)*2+n_][2]); \
        float t3 = tanh_fast(acc[(mh)*4+m_][(nh)*2+n_][3]); \
        union { unsigned char cb[4]; unsigned int u; } p_; \
        p_.cb[0]=f2fp8(t0); p_.cb[1]=f2fp8(t1); p_.cb[2]=f2fp8(t2); p_.cb[3]=f2fp8(t3); \
        *(unsigned int*)&ht8[(((size_t)(h_>>4)*(BB>>4) + (b_>>4))<<8) + ((h_&15)<<4) + (b_&15)] = p_.u; \
        hidden[(size_t)(b_+0)*HH + h_] = t0; \
        hidden[(size_t)(b_+1)*HH + h_] = t1; \
        hidden[(size_t)(b_+2)*HH + h_] = t2; \
        hidden[(size_t)(b_+3)*HH + h_] = t3; \
    }}}

// GEMM1: hidden[b][h]=tanh(xf·wt); ht8 = fp8(tanh) micro-tiled [h>>4][b>>4][h&15][b&15].
__global__ __launch_bounds__(512,2) void k_gemm1(const f16* __restrict__ xf,
                                                 const f16* __restrict__ wt,
                                                 float* __restrict__ hidden,
                                                 unsigned char* __restrict__ ht8){
    __shared__ char sm[131072];
    const int bid = (int)blockIdx.x;
    const int swz = (bid & 7)*64 + (bid >> 3);
    const int btile = swz >> 2, htile = swz & 3;
    const int arow0 = btile*256, brow0 = htile*256;

    const int t = threadIdx.x, lane = t & 63, wid = t >> 6;
    const int wr = wid >> 2, wc = wid & 3;
    const int fr = lane & 15, kg = lane >> 4;
    char* const A0 = sm;
    char* const B0 = sm + 32768;
    char* const A1 = sm + 65536;
    char* const B1 = sm + 98304;
    const int rowA = wr*16384 + fr*128;
    const int rowB = (wc>>1)*16384 + (wc&1)*8192 + fr*128;
    const int ksw0 = ((kg    ) ^ (fr & 7)) << 4;
    const int ksw1 = ((kg + 4) ^ (fr & 7)) << 4;
    const int b_base = btile*256 + wr*128 + kg*4;
    const int h_base = htile*256 + wc*64 + fr;

    f32x4 acc[8][4] = {};
    f16x8 af[4][2], bf[4][2];

    // prologue: K0 -> buf0 (4 half-tiles), K1 -> B1 half0, A1 half0
    stage_half(xf, II, arow0 +   0,  0, A0,         wid, lane);
    stage_half(xf, II, arow0 + 128,  0, A0 + 16384, wid, lane);
    stage_half(wt, II, brow0 +   0,  0, B0,         wid, lane);
    stage_half(wt, II, brow0 + 128,  0, B0 + 16384, wid, lane);
    stage_half(wt, II, brow0 +   0, 64, B1,         wid, lane);
    stage_half(xf, II, arow0 +   0, 64, A1,         wid, lane);
    asm volatile("s_waitcnt vmcnt(4)" ::: "memory");
    __builtin_amdgcn_s_barrier();

    const int ni = NT1 >> 1;     // 8
    for (int it = 0; it < ni-1; ++it){       // main: K-tiles 0..13, stages 0..15 exactly once
        const int k1 = (2*it + 1) * 64;
        const int k2 = (2*it + 2) * 64;
        const int k3 = (2*it + 3) * 64;
        RD_A(A0, 0); RD_B(B0, 0);
        stage_half(xf, II, arow0 + 128, k1, A1 + 16384, wid, lane);
        LGKM8; PH_SYNC1; MFMA_Q(0,0); PH_SYNC2;
        RD_B(B0, 1);
        stage_half(wt, II, brow0 + 128, k1, B1 + 16384, wid, lane);
        PH_SYNC1; MFMA_Q(0,1); PH_SYNC2;
        RD_A(A0, 1);
        stage_half(wt, II, brow0 +   0, k2, B0, wid, lane);
        PH_SYNC1; MFMA_Q(1,0); PH_SYNC2;
        stage_half(xf, II, arow0 +   0, k2, A0, wid, lane);
        PH_SYNC1; MFMA_Q(1,1);
        asm volatile("s_waitcnt vmcnt(4)" ::: "memory");
        __builtin_amdgcn_s_barrier();
        RD_A(A1, 0); RD_B(B1, 0);
        stage_half(xf, II, arow0 + 128, k2, A0 + 16384, wid, lane);
        LGKM8; PH_SYNC1; MFMA_Q(0,0); PH_SYNC2;
        RD_B(B1, 1);
        stage_half(wt, II, brow0 + 128, k2, B0 + 16384, wid, lane);
        PH_SYNC1; MFMA_Q(0,1); PH_SYNC2;
        RD_A(A1, 1);
        stage_half(wt, II, brow0 +   0, k3, B1, wid, lane);
        PH_SYNC1; MFMA_Q(1,0); PH_SYNC2;
        stage_half(xf, II, arow0 +   0, k3, A1, wid, lane);
        PH_SYNC1; MFMA_Q(1,1);
        asm volatile("s_waitcnt vmcnt(4)" ::: "memory");
        __builtin_amdgcn_s_barrier();
    }

    // peeled tail: K-tiles 14 (buf0) and 15 (buf1); completes tile-15 halves,
    // then barrier-free finish with fused per-quadrant epilogue.
    {
        const int kL = (NT1-1)*64;           // 960
        RD_A(A0, 0); RD_B(B0, 0);
        stage_half(xf, II, arow0 + 128, kL, A1 + 16384, wid, lane);
        LGKM0SB; MFMA_Q(0,0);
        RD_B(B0, 1);
        stage_half(wt, II, brow0 + 128, kL, B1 + 16384, wid, lane);
        LGKM0SB; MFMA_Q(0,1);
        RD_A(A0, 1);
        LGKM0SB; MFMA_Q(1,0);
        MFMA_Q(1,1);
        asm volatile("s_waitcnt vmcnt(0)" ::: "memory");
        __builtin_amdgcn_s_barrier();
        RD_A(A1, 0); RD_B(B1, 0);
        LGKM0SB; MFMA_Q(0,0); EPI_Q(0,0);
        RD_B(B1, 1);
        LGKM0SB; MFMA_Q(0,1); EPI_Q(0,1);
        RD_A(A1, 1);
        LGKM0SB; MFMA_Q(1,0); EPI_Q(1,0);
        MFMA_Q(1,1); EPI_Q(1,1);
    }
}

// ================= GEMM2 (fp8 in, fp8 partials out) =================
template<bool MT>
__device__ __forceinline__ void stage_half8(const unsigned char* __restrict__ panel, int ld,
                                            int row0, int kcol0, char* lds_half,
                                            int wid, int lane){
    int o  = wid*1024 + lane*16;
    int rr = o>>6;
    int c  = (o&63) ^ ((rr&6)<<3);
    if constexpr (!MT){
        gload16(panel + (size_t)(row0+rr)*ld + kcol0 + c, lds_half + wid*1024);
    } else {
        int h = row0 + rr;
        int babs = kcol0 + c;
        gload16(panel + (((size_t)(h>>4)*(BB>>4) + (babs>>4))<<8) + ((h&15)<<4) + (babs&15),
                lds_half + wid*1024);
    }
}

#define RD_A8(BUFA, mh) { \
    _Pragma("unroll") for (int m_=0;m_<4;++m_){ \
        afl[m_][0] = *(const long*)((BUFA) + rowA8 + (mh)*4096 + m_*1024 + k80); \
        afl[m_][1] = *(const long*)((BUFA) + rowA8 + (mh)*4096 + m_*1024 + k81); }}

#define RD_B8(BUFB, nh) { \
    _Pragma("unroll") for (int n_=0;n_<2;++n_){ \
        bfl[(nh)*2+n_][0] = *(const long*)((BUFB) + rowB8 + (nh)*2048 + n_*1024 + k80); \
        bfl[(nh)*2+n_][1] = *(const long*)((BUFB) + rowB8 + (nh)*2048 + n_*1024 + k81); }}

#define MFMA_Q8(mh,nh) { \
    __builtin_amdgcn_s_setprio(1); \
    _Pragma("unroll") for (int m_=0;m_<4;++m_){ \
      _Pragma("unroll") for (int n_=0;n_<2;++n_){ \
        _Pragma("unroll") for (int ks_=0;ks_<2;++ks_){ \
          acc[(mh)*4+m_][(nh)*2+n_] = __builtin_amdgcn_mfma_f32_16x16x32_fp8_fp8( \
              afl[m_][ks_], bfl[(nh)*2+n_][ks_], acc[(mh)*4+m_][(nh)*2+n_], 0,0,0); }}} \
    __builtin_amdgcn_s_setprio(0); }

__global__ __launch_bounds__(512,2) void k_gemm2(const unsigned char* __restrict__ xt8,
                                                 const unsigned char* __restrict__ ht8,
                                                 unsigned char* __restrict__ part){
    __shared__ char sm[65536];           // A0 16K | B0 16K | A1 16K | B1 16K
    const int bid = (int)blockIdx.x;
    const int swz = (bid & 7)*32 + (bid >> 3);
    const int split = swz >> 4, tile = swz & 15;
    const int itile = tile & 3, htile = tile >> 2;
    const int arow0 = itile*256, brow0 = htile*256, kbase = split*KCH;

    const int t = threadIdx.x, lane = t & 63, wid = t >> 6;
    const int wr = wid >> 2, wc = wid & 3;
    const int fr = lane & 15, kg = lane >> 4;
    const int mask = NT2 - 1;
    char* const A0 = sm;
    char* const B0 = sm + 16384;
    char* const A1 = sm + 32768;
    char* const B1 = sm + 49152;
    const int rowA8 = wr*8192 + fr*64;
    const int rowB8 = (wc>>1)*8192 + (wc&1)*4096 + fr*64;
    const int s6  = fr & 6;
    const int k80 = ((kg    ) ^ s6) << 3;
    const int k81 = ((kg + 4) ^ s6) << 3;

    f32x4 acc[8][4] = {};
    long afl[4][2], bfl[4][2];

    stage_half8<false>(xt8, BB, arow0 +   0, kbase +  0, A0,        wid, lane);
    stage_half8<false>(xt8, BB, arow0 + 128, kbase +  0, A0 + 8192, wid, lane);
    stage_half8<true >(ht8, BB, brow0 +   0, kbase +  0, B0,        wid, lane);
    stage_half8<true >(ht8, BB, brow0 + 128, kbase +  0, B0 + 8192, wid, lane);
    stage_half8<true >(ht8, BB, brow0 +   0, kbase + 64, B1,        wid, lane);
    stage_half8<false>(xt8, BB, arow0 +   0, kbase + 64, A1,        wid, lane);
    asm volatile("s_waitcnt vmcnt(2)" ::: "memory");
    __builtin_amdgcn_s_barrier();

    const int ni = NT2 >> 1;
    for (int it = 0; it < ni; ++it){
        const int k1 = (2*it + 1) * 64;
        const int k2 = ((2*it + 2) & mask) * 64;
        const int k3 = ((2*it + 3) & mask) * 64;
        RD_A8(A0, 0); RD_B8(B0, 0);
        stage_half8<false>(xt8, BB, arow0 + 128, kbase + k1, A1 + 8192, wid, lane);
        PH_SYNC1; MFMA_Q8(0,0); PH_SYNC2;
        RD_B8(B0, 1);
        stage_half8<true>(ht8, BB, brow0 + 128, kbase + k1, B1 + 8192, wid, lane);
        PH_SYNC1; MFMA_Q8(0,1); PH_SYNC2;
        RD_A8(A0, 1);
        stage_half8<true>(ht8, BB, brow0 +   0, kbase + k2, B0, wid, lane);
        PH_SYNC1; MFMA_Q8(1,0); PH_SYNC2;
        stage_half8<false>(xt8, BB, arow0 +   0, kbase + k2, A0, wid, lane);
        PH_SYNC1; MFMA_Q8(1,1);
        asm volatile("s_waitcnt vmcnt(2)" ::: "memory");
        __builtin_amdgcn_s_barrier();
        RD_A8(A1, 0); RD_B8(B1, 0);
        stage_half8<false>(xt8, BB, arow0 + 128, kbase + k2, A0 + 8192, wid, lane);
        PH_SYNC1; MFMA_Q8(0,0); PH_SYNC2;
        RD_B8(B1, 1);
        stage_half8<true>(ht8, BB, brow0 + 128, kbase + k2, B0 + 8192, wid, lane);
        PH_SYNC1; MFMA_Q8(0,1); PH_SYNC2;
        RD_A8(A1, 1);
        stage_half8<true>(ht8, BB, brow0 +   0, kbase + k3, B1, wid, lane);
        PH_SYNC1; MFMA_Q8(1,0); PH_SYNC2;
        stage_half8<false>(xt8, BB, arow0 +   0, kbase + k3, A1, wid, lane);
        PH_SYNC1; MFMA_Q8(1,1);
        asm volatile("s_waitcnt vmcnt(2)" ::: "memory");
        __builtin_amdgcn_s_barrier();
    }
    asm volatile("s_waitcnt vmcnt(0)" ::: "memory");
    __builtin_amdgcn_s_barrier();

    const size_t pb = (size_t)split*II*HH;
    #pragma unroll
    for (int mf=0; mf<8; ++mf){
        const int i0 = itile*256 + wr*128 + mf*16 + kg*4;
        #pragma unroll
        for (int nf=0; nf<4; ++nf){
            const int h = htile*256 + wc*64 + nf*16 + fr;
            union { unsigned char cb[4]; unsigned int u; } p;
            p.cb[0] = f2fp8(acc[mf][nf][0]);
            p.cb[1] = f2fp8(acc[mf][nf][1]);
            p.cb[2] = f2fp8(acc[mf][nf][2]);
            p.cb[3] = f2fp8(acc[mf][nf][3]);
            *(unsigned int*)&part[pb + (((size_t)(i0>>4)*(HH>>4) + (h>>4))<<8) + ((h&15)<<4) + (i0&15)] = p.u;
        }
    }
}

// k_final: sum 16 fp8 partial planes, apply clip(W + SCALE*delta). 16 elems/thread.
__global__ __launch_bounds__(256) void k_final(const unsigned char* __restrict__ part,
                                               const float* __restrict__ W,
                                               float* __restrict__ outW){
    const int T = (int)blockIdx.x*256 + threadIdx.x;   // 0..65535
    const int mt = T >> 4;                             // micro-tile (i>>4)*64+(h>>4)
    const int hl = T & 15;
    const int i0 = (mt >> 6)*16;
    const int h  = (mt & 63)*16 + hl;
    const size_t po = ((size_t)mt << 8) + (hl << 4);
    float s[16] = {};
    #pragma unroll
    for (int sp=0; sp<SPLIT; ++sp){
        union { f32x4 v; unsigned char cb[16]; } u;
        u.v = __builtin_nontemporal_load((const f32x4*)&part[(size_t)sp*1048576 + po]);
        #pragma unroll
        for (int e=0;e<16;++e) s[e] += fp82f(u.cb[e]);
    }
    const float SCALE = 3.0517578125e-07f;  // 0.01 / 32768
    #pragma unroll
    for (int e=0;e<16;++e){
        const size_t o = (size_t)(i0+e)*HH + h;
        float r = fminf(1.f, fmaxf(-1.f, fmaf(SCALE, s[e], W[o])));
        __builtin_nontemporal_store(r, &outW[o]);
    }
}

extern "C" void kernel_launch(void* const* d_in, const int* in_sizes, int n_in,
                              void* d_out, int out_size, void* d_ws, size_t ws_size,
                              hipStream_t stream){
    (void)in_sizes; (void)n_in; (void)out_size; (void)ws_size;
    const float* x = (const float*)d_in[0];
    const float* W = (const float*)d_in[1];
    float* hidden = (float*)d_out;
    float* outW   = hidden + (size_t)BB*HH;
    char* ws = (char*)d_ws;
    // ws: xf f16 @0 (64MB) | xt8 fp8 @64M (32MB) | ht8 fp8 @96M (32MB) | wt f16 @128M (2MB)
    //     part fp8 [16][I][H] (micro) @0 (16MB, overlaps dead xf)
    f16*           xf   = (f16*)(ws);
    unsigned char* xt8  = (unsigned char*)(ws + 67108864ull);
    unsigned char* ht8  = (unsigned char*)(ws + 100663296ull);
    f16*           wt   = (f16*)(ws + 134217728ull);
    unsigned char* part = (unsigned char*)(ws);

    k_prep2<<<dim3(528, 16), 256, 0, stream>>>(x, xf, xt8, W, wt);
    k_gemm1<<<dim3((BB/256)*(HH/256)), 512, 0, stream>>>(xf, wt, hidden, ht8);
    k_gemm2<<<dim3(16*SPLIT), 512, 0, stream>>>(xt8, ht8, part);
    k_final<<<dim3((II*HH)/(256*16)), 256, 0, stream>>>(part, W, outW);
}